// Round 3
// baseline (1465.503 us; speedup 1.0000x reference)
//
#include <hip/hip_runtime.h>

#define NB 32
#define NT 120
#define NG 25
#define ND 256
#define NH 8
#define NHD 32
#define NTH 512

typedef unsigned short u16;
typedef unsigned int u32;

typedef __bf16 bf16x8 __attribute__((ext_vector_type(8)));
typedef float  f32x4  __attribute__((ext_vector_type(4)));

// ---- LDS layout (dynamic, 80448 B -> 2 blocks/CU if regs <= 128) ----
// hs    : split-bf16 A operand, 25 rows (h -> att -> x1), masked frag loads
// plane0: adj (P0-P1) | Q swz (P2q-P3) | V (P2v-P5) | wred/mu/rsd (P7,P9)
// plane1: K swz (P2k-P3) | ss [25][64] (P4-P5) | z (P6-P7) | fc (P8-P9)
#define SB 264                    // u16 row stride for hs
#define SQ 260                    // f32 row stride for planes
#define OFF_HS_HI 0               // u16[25*264] = 13200 B
#define OFF_HS_LO 13200
#define OFF_P0    26400           // f32[25*260] = 26000 B
#define OFF_P1    52400           // f32[25*260] = 26000 B
#define OFF_SM    78400           // f32[8][64]  = 2048 B (softmax cross-part)
#define SMEM_TOT  80448
#define OFF_WRED  26400           // f32[8][13][2] = 832 (aliases plane0, V dead)
#define OFF_MU    27232           // f32[25]
#define OFF_RSD   27344           // f32[25]

// ---- ws split-weight plane offsets (u16 elements) ----
#define WS_QKV_HI 0
#define WS_QKV_LO 196608
#define WS_WO_HI  393216
#define WS_WO_LO  458752
#define WS_WFC_HI 524288
#define WS_WFC_LO 589824
#define WS_NEED_BYTES (655360ull * 2ull)   // 1,310,720 B

__device__ __forceinline__ float bf2f(u16 u) { return __uint_as_float(((u32)u) << 16); }
__device__ __forceinline__ u16 f2bf(float f) {   // round-to-nearest-even
    u32 x = __float_as_uint(f);
    return (u16)((x + 0x7FFFu + ((x >> 16) & 1u)) >> 16);
}
__device__ __forceinline__ void splitf(float v, u16& h, u16& l) {
    h = f2bf(v);
    l = f2bf(v - bf2f(h));   // residual ~2^-18 rel
}
__device__ __forceinline__ bf16x8 ld_bf8(const u16* p) {   // p 16B-aligned
    uint4 u = *(const uint4*)p;
    return __builtin_bit_cast(bf16x8, u);
}
__device__ __forceinline__ bf16x8 zero_bf8() {
    uint4 z{0u, 0u, 0u, 0u};
    return __builtin_bit_cast(bf16x8, z);
}

// Build split-weight workspace: hi/lo bf16 planes, row-major [rows][256].
__global__ __launch_bounds__(256)
void prep_w(const float* __restrict__ Wq, const float* __restrict__ Wk,
            const float* __restrict__ Wv, const float* __restrict__ Wo,
            const float* __restrict__ Wfc, u16* __restrict__ ws) {
    int e = blockIdx.x * 256 + threadIdx.x;     // 0 .. 327679
    float v; int hi_base, lo_base, idx;
    if (e < 196608) {                            // stacked Q,K,V rows 0..767
        int n = e >> 8, k = e & 255;
        const float* W = (n < 256) ? Wq : (n < 512 ? Wk : Wv);
        v = W[(n & 255) * 256 + k];
        hi_base = WS_QKV_HI; lo_base = WS_QKV_LO; idx = e;
    } else if (e < 262144) {
        idx = e - 196608; v = Wo[idx];
        hi_base = WS_WO_HI; lo_base = WS_WO_LO;
    } else {
        idx = e - 262144; v = Wfc[idx];
        hi_base = WS_WFC_HI; lo_base = WS_WFC_LO;
    }
    u16 h, l; splitf(v, h, l);
    ws[hi_base + idx] = h;
    ws[lo_base + idx] = l;
}

// 512-thread norm stats: waves 0-3 hold g 0-12 (rep 0), waves 4-7 g 13-24.
__device__ __forceinline__ void norm_stats8(const float* zv, int gn,
                                            int lane, int wid, int tid,
                                            float (*s_wred)[13][2], float* s_mu, float* s_rsd) {
    #pragma unroll
    for (int i = 0; i < 13; ++i) {
        if (i >= gn) break;
        float s = zv[i], q = zv[i] * zv[i];
        #pragma unroll
        for (int off = 32; off > 0; off >>= 1) {
            s += __shfl_xor(s, off, 64);
            q += __shfl_xor(q, off, 64);
        }
        if (lane == 0) { s_wred[wid][i][0] = s; s_wred[wid][i][1] = q; }
    }
    __syncthreads();
    if (tid < NG) {
        const int g = tid;
        const int wb = (g < 13) ? 0 : 4, lg = (g < 13) ? g : g - 13;
        float s = 0.f, q = 0.f;
        #pragma unroll
        for (int w = 0; w < 4; ++w) { s += s_wred[wb + w][lg][0]; q += s_wred[wb + w][lg][1]; }
        float mu = s * (1.f / 256.f);
        float var = fmaxf((q - 256.f * mu * mu) * (1.f / 255.f), 0.f);  // ddof=1
        s_mu[g] = mu;
        s_rsd[g] = 1.f / (sqrtf(var) + 1e-6f);
    }
    __syncthreads();
}

// B-fragment: rows of row-major [rows][256] weights (split planes in ws, or inline f32).
template<bool PREP>
__device__ __forceinline__ void load_bfrag(const u16* wshi, const u16* wslo,
                                           const float* Wf, int row, int koff,
                                           bf16x8& bh, bf16x8& bl) {
    if constexpr (PREP) {
        const int off = row * 256 + koff;
        bh = ld_bf8(wshi + off);
        bl = ld_bf8(wslo + off);
    } else {
        const float* p = Wf + row * 256 + koff;
        float4 w0 = *(const float4*)p, w1 = *(const float4*)(p + 4);
        float wv[8] = {w0.x, w0.y, w0.z, w0.w, w1.x, w1.y, w1.z, w1.w};
        union { u16 s[8]; bf16x8 v; } H, L;
        #pragma unroll
        for (int j = 0; j < 8; ++j) splitf(wv[j], H.s[j], L.s[j]);
        bh = H.v; bl = L.v;
    }
}

// Lean single-buffered GEMM: 2 B-tiles/wave, 8 K-steps.
// Caller preloads bh/bl for k=0; B loads issue first each step (VMEM latency
// overlaps the LDS A-reads and prior MFMAs); acc must be zero-initialized.
template<typename FA, typename FB>
__device__ __forceinline__ void run_gemm(FA&& ldA, FB&& ldB,
                                         bf16x8 (&bh)[2], bf16x8 (&bl)[2],
                                         f32x4 (&acc)[2][2]) {
    bf16x8 ah[2], al[2];
    #pragma unroll
    for (int ki = 0; ki < 8; ++ki) {
        if (ki) ldB(32 * ki, bh, bl);
        ldA(32 * ki, ah, al);
        #pragma unroll
        for (int j = 0; j < 2; ++j)
            #pragma unroll
            for (int mt = 0; mt < 2; ++mt)
                acc[mt][j] = __builtin_amdgcn_mfma_f32_16x16x32_bf16(ah[mt], bh[j], acc[mt][j], 0, 0, 0);
        #pragma unroll
        for (int j = 0; j < 2; ++j)
            #pragma unroll
            for (int mt = 0; mt < 2; ++mt)
                acc[mt][j] = __builtin_amdgcn_mfma_f32_16x16x32_bf16(al[mt], bh[j], acc[mt][j], 0, 0, 0);
        #pragma unroll
        for (int j = 0; j < 2; ++j)
            #pragma unroll
            for (int mt = 0; mt < 2; ++mt)
                acc[mt][j] = __builtin_amdgcn_mfma_f32_16x16x32_bf16(ah[mt], bl[j], acc[mt][j], 0, 0, 0);
    }
}

template<bool PREP>
__global__ __launch_bounds__(NTH, 4)
void enc_mfma(const float* __restrict__ x,  const float* __restrict__ adj,
              const float* __restrict__ Wq, const float* __restrict__ bq,
              const float* __restrict__ Wk, const float* __restrict__ bk,
              const float* __restrict__ Wv, const float* __restrict__ bv,
              const float* __restrict__ Wo, const float* __restrict__ bo,
              const float* __restrict__ Wfc,const float* __restrict__ bfc,
              const float* __restrict__ alpha, const float* __restrict__ beta,
              float* __restrict__ out, const u16* __restrict__ ws)
{
    extern __shared__ char smem[];
    u16*   hs_hi  = (u16*)(smem + OFF_HS_HI);
    u16*   hs_lo  = (u16*)(smem + OFF_HS_LO);
    float* plane0 = (float*)(smem + OFF_P0);
    float* plane1 = (float*)(smem + OFF_P1);
    float* s_sm   = (float*)(smem + OFF_SM);
    float (*s_wred)[13][2] = (float(*)[13][2])(smem + OFF_WRED);
    float* s_mu  = (float*)(smem + OFF_MU);
    float* s_rsd = (float*)(smem + OFF_RSD);

    const int bt = blockIdx.x;
    const int tid = threadIdx.x;
    const int d = tid & 255, rep = tid >> 8;
    const int lane = tid & 63, wid = tid >> 6;          // wave id 0-7
    const int lm = lane & 15, quad = lane >> 4;
    const int g0 = rep ? 13 : 0, gn = rep ? 12 : 13;
    const long base = (long)bt * (NG * ND);

    // ---- fragment load helpers ----
    // A tile rows: mt=0 -> rows 0..15 (valid), mt=1 -> rows 16..31; rows >= 25 zero.
    auto loadA = [&](int k0, bf16x8 (&ah)[2], bf16x8 (&al)[2]) {
        const int koff = k0 + quad * 8;
        ah[0] = ld_bf8(hs_hi + lm * SB + koff);
        al[0] = ld_bf8(hs_lo + lm * SB + koff);
        if (lm < 9) {
            ah[1] = ld_bf8(hs_hi + (16 + lm) * SB + koff);
            al[1] = ld_bf8(hs_lo + (16 + lm) * SB + koff);
        } else {
            ah[1] = zero_bf8();
            al[1] = zero_bf8();
        }
    };
    // 2-tile B loads: rows wid*32 + j*16 + lm of each weight matrix.
    auto loadB_q = [&](int k0, bf16x8 (&bh)[2], bf16x8 (&bl)[2]) {
        const int koff = k0 + quad * 8;
        #pragma unroll
        for (int j = 0; j < 2; ++j)
            load_bfrag<PREP>(ws + WS_QKV_HI, ws + WS_QKV_LO, Wq,
                             wid * 32 + j * 16 + lm, koff, bh[j], bl[j]);
    };
    auto loadB_k = [&](int k0, bf16x8 (&bh)[2], bf16x8 (&bl)[2]) {
        const int koff = k0 + quad * 8;
        #pragma unroll
        for (int j = 0; j < 2; ++j)
            load_bfrag<PREP>(ws + WS_QKV_HI, ws + WS_QKV_LO, Wk,
                             PREP ? (256 + wid * 32 + j * 16 + lm) : (wid * 32 + j * 16 + lm),
                             koff, bh[j], bl[j]);
    };
    auto loadB_v = [&](int k0, bf16x8 (&bh)[2], bf16x8 (&bl)[2]) {
        const int koff = k0 + quad * 8;
        #pragma unroll
        for (int j = 0; j < 2; ++j)
            load_bfrag<PREP>(ws + WS_QKV_HI, ws + WS_QKV_LO, Wv,
                             PREP ? (512 + wid * 32 + j * 16 + lm) : (wid * 32 + j * 16 + lm),
                             koff, bh[j], bl[j]);
    };
    auto loadB_wo = [&](int k0, bf16x8 (&bh)[2], bf16x8 (&bl)[2]) {
        const int koff = k0 + quad * 8;
        #pragma unroll
        for (int j = 0; j < 2; ++j)
            load_bfrag<PREP>(ws + WS_WO_HI, ws + WS_WO_LO, Wo,
                             wid * 32 + j * 16 + lm, koff, bh[j], bl[j]);
    };
    auto loadB_wfc = [&](int k0, bf16x8 (&bh)[2], bf16x8 (&bl)[2]) {
        const int koff = k0 + quad * 8;
        #pragma unroll
        for (int j = 0; j < 2; ++j)
            load_bfrag<PREP>(ws + WS_WFC_HI, ws + WS_WFC_LO, Wfc,
                             wid * 32 + j * 16 + lm, koff, bh[j], bl[j]);
    };
    // Epilogue store: rows < 25 of C[25,256] into plane, optional swizzle / relu.
    auto store_c = [&](f32x4 (&acc)[2][2], float b0, float b1,
                       float* plane, bool swz, bool relu) {
        float bbv[2] = { b0, b1 };
        #pragma unroll
        for (int nt = 0; nt < 2; ++nt) {
            const int col = wid * 32 + nt * 16 + lm;
            const int pcol = swz ? (col ^ ((col >> 3) & 0x1C)) : col;
            #pragma unroll
            for (int mt = 0; mt < 2; ++mt)
                #pragma unroll
                for (int i = 0; i < 4; ++i) {
                    const int r = mt * 16 + quad * 4 + i;
                    if (mt == 0 || r < 25) {
                        float v = acc[mt][nt][i] + bbv[nt];
                        if (relu) v = fmaxf(v, 0.f);
                        plane[r * SQ + pcol] = v;
                    }
                }
        }
    };

    // single-buffer fragment registers (slot preloaded before each GEMM's barrier)
    bf16x8 bhB[2], blB[2];           // shared across GEMM phases (lifetimes disjoint)
    float zx[13];                    // this thread's x residual rows
    float zv[13];                    // z / x1 rows

    // ---- P0: stage adjacency into plane0; prefetch alpha/beta ----
    for (int i = tid; i < NG * NG; i += NTH) plane0[i] = adj[i];
    const float af = alpha[d], bef = beta[d];
    __syncthreads();

    // ---- P1: h = adj @ x (VALU, f32), write split-bf16 (25 rows); stash x residual ----
    {
        float acc[13];
        #pragma unroll
        for (int i = 0; i < 13; ++i) acc[i] = 0.f;
        #pragma unroll
        for (int n = 0; n < NG; ++n) {
            float xv = x[base + n * ND + d];
            if (rep == 0) { if (n < 13) zx[n] = xv; }
            else          { if (n >= 13) zx[n - 13] = xv; }
            #pragma unroll
            for (int i = 0; i < 13; ++i)
                acc[i] += plane0[(g0 + i) * NG + n] * xv;  // i==12,rep1 reads in-bounds scratch; never stored
        }
        #pragma unroll
        for (int i = 0; i < 13; ++i) {
            if (i >= gn) break;
            u16 h, l; splitf(acc[i], h, l);
            hs_hi[(g0 + i) * SB + d] = h; hs_lo[(g0 + i) * SB + d] = l;
        }
    }
    loadB_q(0, bhB, blB);            // prefetch Q k=0 B-frags across the barrier
    __syncthreads();

    // ---- P2q: Q GEMM. C[25,256] -> plane0 swizzled (adj dead after barrier) ----
    {
        f32x4 acc[2][2];
        #pragma unroll
        for (int mt = 0; mt < 2; ++mt)
            #pragma unroll
            for (int nt = 0; nt < 2; ++nt) acc[mt][nt] = (f32x4)0.f;
        run_gemm(loadA, loadB_q, bhB, blB, acc);
        store_c(acc, bq[wid * 32 + lm], bq[wid * 32 + 16 + lm], plane0, true, false);
    }
    // ---- P2k: K GEMM. C[25,256] -> plane1 swizzled. (reads only stable hs/ws: no barrier) ----
    {
        f32x4 acc[2][2];
        #pragma unroll
        for (int mt = 0; mt < 2; ++mt)
            #pragma unroll
            for (int nt = 0; nt < 2; ++nt) acc[mt][nt] = (f32x4)0.f;
        loadB_k(0, bhB, blB);
        run_gemm(loadA, loadB_k, bhB, blB, acc);
        store_c(acc, bk[wid * 32 + lm], bk[wid * 32 + 16 + lm], plane1, true, false);
    }
    __syncthreads();

    // ---- P3: scores[g][h1][h2] = Q_g K_g^T / sqrt(32), kept in registers ----
    float sreg[4];
    {
        #pragma unroll
        for (int kk = 0; kk < 4; ++kk) {
            const int i = tid + kk * NTH;
            const int ii = (i < NG * 64) ? i : 0;        // lanes past 1600 compute a dummy
            const int g = ii >> 6, hh = ii & 63;
            const int jq = hh >> 3, jk = hh & 7;
            const float4* q4 = (const float4*)(plane0 + g * SQ + jq * 32);
            const float4* k4 = (const float4*)(plane1 + g * SQ + jk * 32);
            float s = 0.f;
            #pragma unroll
            for (int c = 0; c < 8; ++c) {
                float4 qa = q4[c ^ jq], ka = k4[c ^ jk];  // unswizzle on read
                s += qa.x * ka.x + qa.y * ka.y + qa.z * ka.z + qa.w * ka.w;
            }
            sreg[kk] = s * 0.17677669529663687f;
        }
    }
    __syncthreads();   // Q,K dead; plane1 reusable for ss

    // ---- P4: softmax over g (dim=1); thread owns g = part+8k at fixed col ----
    {
        const int col = tid & 63, part = tid >> 6;
        float m = -1e30f;
        #pragma unroll
        for (int kk = 0; kk < 4; ++kk)
            if (tid + kk * NTH < NG * 64) m = fmaxf(m, sreg[kk]);
        s_sm[part * 64 + col] = m;
        __syncthreads();
        float cm = -1e30f;
        #pragma unroll
        for (int p = 0; p < 8; ++p) cm = fmaxf(cm, s_sm[p * 64 + col]);
        __syncthreads();                          // all reads done before overwrite
        float den = 0.f;
        #pragma unroll
        for (int kk = 0; kk < 4; ++kk)
            if (tid + kk * NTH < NG * 64) {
                float e = expf(sreg[kk] - cm);
                sreg[kk] = e;
                den += e;
            }
        s_sm[part * 64 + col] = den;
        __syncthreads();
        float tden = 0.f;
        #pragma unroll
        for (int p = 0; p < 8; ++p) tden += s_sm[p * 64 + col];
        const float inv = 1.f / tden;
        #pragma unroll
        for (int kk = 0; kk < 4; ++kk) {
            const int i = tid + kk * NTH;
            if (i < NG * 64) plane1[i] = sreg[kk] * inv;   // ss -> K region
        }
    }
    loadB_v(0, bhB, blB);            // prefetch V k=0 B-frags across the barrier
    __syncthreads();

    // ---- P2v: V GEMM. C[25,256] -> plane0 (Q dead), unswizzled ----
    {
        f32x4 acc[2][2];
        #pragma unroll
        for (int mt = 0; mt < 2; ++mt)
            #pragma unroll
            for (int nt = 0; nt < 2; ++nt) acc[mt][nt] = (f32x4)0.f;
        run_gemm(loadA, loadB_v, bhB, blB, acc);
        store_c(acc, bv[wid * 32 + lm], bv[wid * 32 + 16 + lm], plane0, false, false);
    }
    __syncthreads();

    // ---- P5: att = w @ V (f32), write split-bf16 into hs ----
    {
        const int h1 = (tid >> 5) & 7, hd = tid & 31;   // col = d
        #pragma unroll
        for (int i = 0; i < 13; ++i) {
            if (i >= gn) break;
            const int g = g0 + i;
            float a = 0.f;
            #pragma unroll
            for (int h2 = 0; h2 < NH; ++h2)
                a += plane1[g * 64 + h1 * 8 + h2] * plane0[g * SQ + h2 * NHD + hd];
            u16 h, l; splitf(a, h, l);
            hs_hi[g * SB + d] = h; hs_lo[g * SB + d] = l;
        }
    }
    loadB_wo(0, bhB, blB);           // prefetch Wo k=0 B-frags across the barrier
    __syncthreads();

    // ---- P6: Wo GEMM. C[25,256] -> plane1 (ss dead) ----
    {
        f32x4 acc[2][2];
        #pragma unroll
        for (int mt = 0; mt < 2; ++mt)
            #pragma unroll
            for (int nt = 0; nt < 2; ++nt) acc[mt][nt] = (f32x4)0.f;
        run_gemm(loadA, loadB_wo, bhB, blB, acc);
        store_c(acc, bo[wid * 32 + lm], bo[wid * 32 + 16 + lm], plane1, false, false);
    }
    __syncthreads();

    // ---- P7: norm1; x residual from regs; write x1 split-bf16 into hs ----
    {
        #pragma unroll
        for (int i = 0; i < 13; ++i) {
            if (i >= gn) break;
            zv[i] = plane1[(g0 + i) * SQ + d] + zx[i];
        }
    }
    norm_stats8(zv, gn, lane, wid, tid, s_wred, s_mu, s_rsd);
    #pragma unroll
    for (int i = 0; i < 13; ++i) {
        if (i >= gn) break;
        const float x1 = af * (zv[i] - s_mu[g0 + i]) * s_rsd[g0 + i] + bef;
        zv[i] = x1;
        u16 h, l; splitf(x1, h, l);
        hs_hi[(g0 + i) * SB + d] = h; hs_lo[(g0 + i) * SB + d] = l;
    }
    loadB_wfc(0, bhB, blB);          // prefetch Wfc k=0 B-frags across the barrier
    __syncthreads();

    // ---- P8: Wfc GEMM; epilogue relu(acc+bfc) -> plane1 ----
    {
        f32x4 acc[2][2];
        #pragma unroll
        for (int mt = 0; mt < 2; ++mt)
            #pragma unroll
            for (int nt = 0; nt < 2; ++nt) acc[mt][nt] = (f32x4)0.f;
        run_gemm(loadA, loadB_wfc, bhB, blB, acc);
        store_c(acc, bfc[wid * 32 + lm], bfc[wid * 32 + 16 + lm], plane1, false, true);
    }
    __syncthreads();

    // ---- P9: norm2 -> out ----
    float z2[13];
    {
        #pragma unroll
        for (int i = 0; i < 13; ++i) {
            if (i >= gn) break;
            z2[i] = zv[i] + plane1[(g0 + i) * SQ + d];
        }
    }
    norm_stats8(z2, gn, lane, wid, tid, s_wred, s_mu, s_rsd);
    #pragma unroll
    for (int i = 0; i < 13; ++i) {
        if (i >= gn) break;
        out[base + (g0 + i) * ND + d] = af * (z2[i] - s_mu[g0 + i]) * s_rsd[g0 + i] + bef;
    }
}

extern "C" void kernel_launch(void* const* d_in, const int* in_sizes, int n_in,
                              void* d_out, int out_size, void* d_ws, size_t ws_size,
                              hipStream_t stream) {
    (void)in_sizes; (void)n_in; (void)out_size;
    const float* x     = (const float*)d_in[0];
    const float* adj   = (const float*)d_in[1];
    const float* Wq    = (const float*)d_in[2];
    const float* bq    = (const float*)d_in[3];
    const float* Wk    = (const float*)d_in[4];
    const float* bk    = (const float*)d_in[5];
    const float* Wv    = (const float*)d_in[6];
    const float* bv    = (const float*)d_in[7];
    const float* Wo    = (const float*)d_in[8];
    const float* bo    = (const float*)d_in[9];
    const float* Wfc   = (const float*)d_in[10];
    const float* bfc   = (const float*)d_in[11];
    const float* alpha = (const float*)d_in[12];
    const float* beta  = (const float*)d_in[13];
    float* out = (float*)d_out;
    u16* ws = (u16*)d_ws;

    const bool prep = (ws_size >= WS_NEED_BYTES);

    hipFuncSetAttribute((const void*)enc_mfma<true>,
                        hipFuncAttributeMaxDynamicSharedMemorySize, SMEM_TOT);
    hipFuncSetAttribute((const void*)enc_mfma<false>,
                        hipFuncAttributeMaxDynamicSharedMemorySize, SMEM_TOT);

    if (prep) {
        prep_w<<<dim3(1280), dim3(256), 0, stream>>>(Wq, Wk, Wv, Wo, Wfc, ws);
        enc_mfma<true><<<dim3(NB * NT), dim3(NTH), SMEM_TOT, stream>>>(
            x, adj, Wq, bq, Wk, bk, Wv, bv, Wo, bo, Wfc, bfc, alpha, beta, out, ws);
    } else {
        enc_mfma<false><<<dim3(NB * NT), dim3(NTH), SMEM_TOT, stream>>>(
            x, adj, Wq, bq, Wk, bk, Wv, bv, Wo, bo, Wfc, bfc, alpha, beta, out, ws);
    }
}

// Round 4
// 991.412 us; speedup vs baseline: 1.4782x; 1.4782x over previous
//
#include <hip/hip_runtime.h>

#define NB 32
#define NT 120
#define NG 25
#define ND 256
#define NH 8
#define NHD 32
#define NTH 512

typedef unsigned short u16;
typedef unsigned int u32;

typedef __bf16 bf16x8 __attribute__((ext_vector_type(8)));
typedef float  f32x4  __attribute__((ext_vector_type(4)));

// ---- LDS layout (dynamic, 80448 B; 2 blocks/CU needs total regs <= 128) ----
// hs    : split-bf16 A operand, 25 rows (h -> att -> x1), masked frag loads
// plane0: adj (P0-P1) | Q swz (P2q-P3) | V (P2v-P5) | wred/mu/rsd (P7,P9)
// plane1: K swz (P2k-P3) | ss [25][64] (P4-P5) | z (P6-P7) | fc (P8-P9)
#define SB 264                    // u16 row stride for hs
#define SQ 260                    // f32 row stride for planes
#define OFF_HS_HI 0               // u16[25*264] = 13200 B
#define OFF_HS_LO 13200
#define OFF_P0    26400           // f32[25*260] = 26000 B
#define OFF_P1    52400           // f32[25*260] = 26000 B
#define OFF_SM    78400           // f32[8][64]  = 2048 B (softmax cross-part)
#define SMEM_TOT  80448
#define OFF_WRED  26400           // f32[8][13][2] = 832 (aliases plane0, V dead)
#define OFF_MU    27232           // f32[25]
#define OFF_RSD   27344           // f32[25]

// ---- ws split-weight plane offsets (u16 elements) ----
#define WS_QKV_HI 0
#define WS_QKV_LO 196608
#define WS_WO_HI  393216
#define WS_WO_LO  458752
#define WS_WFC_HI 524288
#define WS_WFC_LO 589824
#define WS_NEED_BYTES (655360ull * 2ull)   // 1,310,720 B

__device__ __forceinline__ float bf2f(u16 u) { return __uint_as_float(((u32)u) << 16); }
__device__ __forceinline__ u16 f2bf(float f) {   // round-to-nearest-even
    u32 x = __float_as_uint(f);
    return (u16)((x + 0x7FFFu + ((x >> 16) & 1u)) >> 16);
}
__device__ __forceinline__ void splitf(float v, u16& h, u16& l) {
    h = f2bf(v);
    l = f2bf(v - bf2f(h));   // residual ~2^-18 rel
}
__device__ __forceinline__ bf16x8 ld_bf8(const u16* p) {   // p 16B-aligned
    uint4 u = *(const uint4*)p;
    return __builtin_bit_cast(bf16x8, u);
}
__device__ __forceinline__ bf16x8 zero_bf8() {
    uint4 z{0u, 0u, 0u, 0u};
    return __builtin_bit_cast(bf16x8, z);
}

// Build split-weight workspace: hi/lo bf16 planes, row-major [rows][256].
__global__ __launch_bounds__(256)
void prep_w(const float* __restrict__ Wq, const float* __restrict__ Wk,
            const float* __restrict__ Wv, const float* __restrict__ Wo,
            const float* __restrict__ Wfc, u16* __restrict__ ws) {
    int e = blockIdx.x * 256 + threadIdx.x;     // 0 .. 327679
    float v; int hi_base, lo_base, idx;
    if (e < 196608) {                            // stacked Q,K,V rows 0..767
        int n = e >> 8, k = e & 255;
        const float* W = (n < 256) ? Wq : (n < 512 ? Wk : Wv);
        v = W[(n & 255) * 256 + k];
        hi_base = WS_QKV_HI; lo_base = WS_QKV_LO; idx = e;
    } else if (e < 262144) {
        idx = e - 196608; v = Wo[idx];
        hi_base = WS_WO_HI; lo_base = WS_WO_LO;
    } else {
        idx = e - 262144; v = Wfc[idx];
        hi_base = WS_WFC_HI; lo_base = WS_WFC_LO;
    }
    u16 h, l; splitf(v, h, l);
    ws[hi_base + idx] = h;
    ws[lo_base + idx] = l;
}

// 512-thread norm stats: waves 0-3 hold g 0-12 (rep 0), waves 4-7 g 13-24.
__device__ __forceinline__ void norm_stats8(const float* zv, int gn,
                                            int lane, int wid, int tid,
                                            float (*s_wred)[13][2], float* s_mu, float* s_rsd) {
    #pragma unroll
    for (int i = 0; i < 13; ++i) {
        if (i >= gn) break;
        float s = zv[i], q = zv[i] * zv[i];
        #pragma unroll
        for (int off = 32; off > 0; off >>= 1) {
            s += __shfl_xor(s, off, 64);
            q += __shfl_xor(q, off, 64);
        }
        if (lane == 0) { s_wred[wid][i][0] = s; s_wred[wid][i][1] = q; }
    }
    __syncthreads();
    if (tid < NG) {
        const int g = tid;
        const int wb = (g < 13) ? 0 : 4, lg = (g < 13) ? g : g - 13;
        float s = 0.f, q = 0.f;
        #pragma unroll
        for (int w = 0; w < 4; ++w) { s += s_wred[wb + w][lg][0]; q += s_wred[wb + w][lg][1]; }
        float mu = s * (1.f / 256.f);
        float var = fmaxf((q - 256.f * mu * mu) * (1.f / 255.f), 0.f);  // ddof=1
        s_mu[g] = mu;
        s_rsd[g] = 1.f / (sqrtf(var) + 1e-6f);
    }
    __syncthreads();
}

// B-fragment: rows of row-major [rows][256] weights (split planes in ws, or inline f32).
template<bool PREP>
__device__ __forceinline__ void load_bfrag(const u16* wshi, const u16* wslo,
                                           const float* Wf, int row, int koff,
                                           bf16x8& bh, bf16x8& bl) {
    if constexpr (PREP) {
        const int off = row * 256 + koff;
        bh = ld_bf8(wshi + off);
        bl = ld_bf8(wslo + off);
    } else {
        const float* p = Wf + row * 256 + koff;
        float4 w0 = *(const float4*)p, w1 = *(const float4*)(p + 4);
        float wv[8] = {w0.x, w0.y, w0.z, w0.w, w1.x, w1.y, w1.z, w1.w};
        union { u16 s[8]; bf16x8 v; } H, L;
        #pragma unroll
        for (int j = 0; j < 8; ++j) splitf(wv[j], H.s[j], L.s[j]);
        bh = H.v; bl = L.v;
    }
}

// Lean single-buffered GEMM: 2 B-tiles/wave, 8 K-steps.
// Caller preloads bh/bl for k=0; B loads issue first each step (VMEM latency
// overlaps the LDS A-reads and prior MFMAs); acc must be zero-initialized.
template<typename FA, typename FB>
__device__ __forceinline__ void run_gemm(FA&& ldA, FB&& ldB,
                                         bf16x8 (&bh)[2], bf16x8 (&bl)[2],
                                         f32x4 (&acc)[2][2]) {
    bf16x8 ah[2], al[2];
    #pragma unroll
    for (int ki = 0; ki < 8; ++ki) {
        if (ki) ldB(32 * ki, bh, bl);
        ldA(32 * ki, ah, al);
        #pragma unroll
        for (int j = 0; j < 2; ++j)
            #pragma unroll
            for (int mt = 0; mt < 2; ++mt)
                acc[mt][j] = __builtin_amdgcn_mfma_f32_16x16x32_bf16(ah[mt], bh[j], acc[mt][j], 0, 0, 0);
        #pragma unroll
        for (int j = 0; j < 2; ++j)
            #pragma unroll
            for (int mt = 0; mt < 2; ++mt)
                acc[mt][j] = __builtin_amdgcn_mfma_f32_16x16x32_bf16(al[mt], bh[j], acc[mt][j], 0, 0, 0);
        #pragma unroll
        for (int j = 0; j < 2; ++j)
            #pragma unroll
            for (int mt = 0; mt < 2; ++mt)
                acc[mt][j] = __builtin_amdgcn_mfma_f32_16x16x32_bf16(ah[mt], bl[j], acc[mt][j], 0, 0, 0);
    }
}

template<bool PREP>
__global__ __launch_bounds__(NTH, 2)
void enc_mfma(const float* __restrict__ x,  const float* __restrict__ adj,
              const float* __restrict__ Wq, const float* __restrict__ bq,
              const float* __restrict__ Wk, const float* __restrict__ bk,
              const float* __restrict__ Wv, const float* __restrict__ bv,
              const float* __restrict__ Wo, const float* __restrict__ bo,
              const float* __restrict__ Wfc,const float* __restrict__ bfc,
              const float* __restrict__ alpha, const float* __restrict__ beta,
              float* __restrict__ out, const u16* __restrict__ ws)
{
    extern __shared__ char smem[];
    u16*   hs_hi  = (u16*)(smem + OFF_HS_HI);
    u16*   hs_lo  = (u16*)(smem + OFF_HS_LO);
    float* plane0 = (float*)(smem + OFF_P0);
    float* plane1 = (float*)(smem + OFF_P1);
    float* s_sm   = (float*)(smem + OFF_SM);
    float (*s_wred)[13][2] = (float(*)[13][2])(smem + OFF_WRED);
    float* s_mu  = (float*)(smem + OFF_MU);
    float* s_rsd = (float*)(smem + OFF_RSD);

    const int bt = blockIdx.x;
    const int tid = threadIdx.x;
    const int d = tid & 255, rep = tid >> 8;
    const int lane = tid & 63, wid = tid >> 6;          // wave id 0-7
    const int lm = lane & 15, quad = lane >> 4;
    const int g0 = rep ? 13 : 0, gn = rep ? 12 : 13;
    const long base = (long)bt * (NG * ND);

    // ---- fragment load helpers ----
    // A tile rows: mt=0 -> rows 0..15 (valid), mt=1 -> rows 16..31; rows >= 25 zero.
    auto loadA = [&](int k0, bf16x8 (&ah)[2], bf16x8 (&al)[2]) {
        const int koff = k0 + quad * 8;
        ah[0] = ld_bf8(hs_hi + lm * SB + koff);
        al[0] = ld_bf8(hs_lo + lm * SB + koff);
        if (lm < 9) {
            ah[1] = ld_bf8(hs_hi + (16 + lm) * SB + koff);
            al[1] = ld_bf8(hs_lo + (16 + lm) * SB + koff);
        } else {
            ah[1] = zero_bf8();
            al[1] = zero_bf8();
        }
    };
    // 2-tile B loads: rows wid*32 + j*16 + lm of each weight matrix.
    auto loadB_q = [&](int k0, bf16x8 (&bh)[2], bf16x8 (&bl)[2]) {
        const int koff = k0 + quad * 8;
        #pragma unroll
        for (int j = 0; j < 2; ++j)
            load_bfrag<PREP>(ws + WS_QKV_HI, ws + WS_QKV_LO, Wq,
                             wid * 32 + j * 16 + lm, koff, bh[j], bl[j]);
    };
    auto loadB_k = [&](int k0, bf16x8 (&bh)[2], bf16x8 (&bl)[2]) {
        const int koff = k0 + quad * 8;
        #pragma unroll
        for (int j = 0; j < 2; ++j)
            load_bfrag<PREP>(ws + WS_QKV_HI, ws + WS_QKV_LO, Wk,
                             PREP ? (256 + wid * 32 + j * 16 + lm) : (wid * 32 + j * 16 + lm),
                             koff, bh[j], bl[j]);
    };
    auto loadB_v = [&](int k0, bf16x8 (&bh)[2], bf16x8 (&bl)[2]) {
        const int koff = k0 + quad * 8;
        #pragma unroll
        for (int j = 0; j < 2; ++j)
            load_bfrag<PREP>(ws + WS_QKV_HI, ws + WS_QKV_LO, Wv,
                             PREP ? (512 + wid * 32 + j * 16 + lm) : (wid * 32 + j * 16 + lm),
                             koff, bh[j], bl[j]);
    };
    auto loadB_wo = [&](int k0, bf16x8 (&bh)[2], bf16x8 (&bl)[2]) {
        const int koff = k0 + quad * 8;
        #pragma unroll
        for (int j = 0; j < 2; ++j)
            load_bfrag<PREP>(ws + WS_WO_HI, ws + WS_WO_LO, Wo,
                             wid * 32 + j * 16 + lm, koff, bh[j], bl[j]);
    };
    auto loadB_wfc = [&](int k0, bf16x8 (&bh)[2], bf16x8 (&bl)[2]) {
        const int koff = k0 + quad * 8;
        #pragma unroll
        for (int j = 0; j < 2; ++j)
            load_bfrag<PREP>(ws + WS_WFC_HI, ws + WS_WFC_LO, Wfc,
                             wid * 32 + j * 16 + lm, koff, bh[j], bl[j]);
    };
    // Epilogue store: rows < 25 of C[25,256] into plane, optional swizzle / relu.
    auto store_c = [&](f32x4 (&acc)[2][2], float b0, float b1,
                       float* plane, bool swz, bool relu) {
        float bbv[2] = { b0, b1 };
        #pragma unroll
        for (int nt = 0; nt < 2; ++nt) {
            const int col = wid * 32 + nt * 16 + lm;
            const int pcol = swz ? (col ^ ((col >> 3) & 0x1C)) : col;
            #pragma unroll
            for (int mt = 0; mt < 2; ++mt)
                #pragma unroll
                for (int i = 0; i < 4; ++i) {
                    const int r = mt * 16 + quad * 4 + i;
                    if (mt == 0 || r < 25) {
                        float v = acc[mt][nt][i] + bbv[nt];
                        if (relu) v = fmaxf(v, 0.f);
                        plane[r * SQ + pcol] = v;
                    }
                }
        }
    };

    // single-buffer fragment registers (slot preloaded before each GEMM's barrier)
    bf16x8 bhB[2], blB[2];           // shared across GEMM phases (lifetimes disjoint)

    // ---- P0: stage adjacency into plane0; prefetch alpha/beta ----
    for (int i = tid; i < NG * NG; i += NTH) plane0[i] = adj[i];
    const float af = alpha[d], bef = beta[d];
    __syncthreads();

    // ---- P1: h = adj @ x (VALU, f32), write split-bf16 (25 rows) ----
    {
        float acc[13];
        #pragma unroll
        for (int i = 0; i < 13; ++i) acc[i] = 0.f;
        #pragma unroll
        for (int n = 0; n < NG; ++n) {
            float xv = x[base + n * ND + d];
            #pragma unroll
            for (int i = 0; i < 13; ++i)
                acc[i] += plane0[(g0 + i) * NG + n] * xv;  // i==12,rep1 reads in-bounds scratch; never stored
        }
        #pragma unroll
        for (int i = 0; i < 13; ++i) {
            if (i >= gn) break;
            u16 h, l; splitf(acc[i], h, l);
            hs_hi[(g0 + i) * SB + d] = h; hs_lo[(g0 + i) * SB + d] = l;
        }
    }
    loadB_q(0, bhB, blB);            // prefetch Q k=0 B-frags across the barrier
    __syncthreads();

    // ---- P2q: Q GEMM. C[25,256] -> plane0 swizzled (adj dead after barrier) ----
    {
        f32x4 acc[2][2];
        #pragma unroll
        for (int mt = 0; mt < 2; ++mt)
            #pragma unroll
            for (int nt = 0; nt < 2; ++nt) acc[mt][nt] = (f32x4)0.f;
        run_gemm(loadA, loadB_q, bhB, blB, acc);
        store_c(acc, bq[wid * 32 + lm], bq[wid * 32 + 16 + lm], plane0, true, false);
    }
    // ---- P2k: K GEMM. C[25,256] -> plane1 swizzled. (reads only stable hs/ws: no barrier) ----
    {
        f32x4 acc[2][2];
        #pragma unroll
        for (int mt = 0; mt < 2; ++mt)
            #pragma unroll
            for (int nt = 0; nt < 2; ++nt) acc[mt][nt] = (f32x4)0.f;
        loadB_k(0, bhB, blB);
        run_gemm(loadA, loadB_k, bhB, blB, acc);
        store_c(acc, bk[wid * 32 + lm], bk[wid * 32 + 16 + lm], plane1, true, false);
    }
    __syncthreads();

    // ---- P3: scores[g][h1][h2] = Q_g K_g^T / sqrt(32), kept in registers ----
    float sreg[4];
    {
        #pragma unroll
        for (int kk = 0; kk < 4; ++kk) {
            const int i = tid + kk * NTH;
            const int ii = (i < NG * 64) ? i : 0;        // lanes past 1600 compute a dummy
            const int g = ii >> 6, hh = ii & 63;
            const int jq = hh >> 3, jk = hh & 7;
            const float4* q4 = (const float4*)(plane0 + g * SQ + jq * 32);
            const float4* k4 = (const float4*)(plane1 + g * SQ + jk * 32);
            float s = 0.f;
            #pragma unroll
            for (int c = 0; c < 8; ++c) {
                float4 qa = q4[c ^ jq], ka = k4[c ^ jk];  // unswizzle on read
                s += qa.x * ka.x + qa.y * ka.y + qa.z * ka.z + qa.w * ka.w;
            }
            sreg[kk] = s * 0.17677669529663687f;
        }
    }
    __syncthreads();   // Q,K dead; plane1 reusable for ss

    // ---- P4: softmax over g (dim=1); thread owns g = part+8k at fixed col ----
    {
        const int col = tid & 63, part = tid >> 6;
        float m = -1e30f;
        #pragma unroll
        for (int kk = 0; kk < 4; ++kk)
            if (tid + kk * NTH < NG * 64) m = fmaxf(m, sreg[kk]);
        s_sm[part * 64 + col] = m;
        __syncthreads();
        float cm = -1e30f;
        #pragma unroll
        for (int p = 0; p < 8; ++p) cm = fmaxf(cm, s_sm[p * 64 + col]);
        __syncthreads();                          // all reads done before overwrite
        float den = 0.f;
        #pragma unroll
        for (int kk = 0; kk < 4; ++kk)
            if (tid + kk * NTH < NG * 64) {
                float e = expf(sreg[kk] - cm);
                sreg[kk] = e;
                den += e;
            }
        s_sm[part * 64 + col] = den;
        __syncthreads();
        float tden = 0.f;
        #pragma unroll
        for (int p = 0; p < 8; ++p) tden += s_sm[p * 64 + col];
        const float inv = 1.f / tden;
        #pragma unroll
        for (int kk = 0; kk < 4; ++kk) {
            const int i = tid + kk * NTH;
            if (i < NG * 64) plane1[i] = sreg[kk] * inv;   // ss -> K region
        }
    }
    loadB_v(0, bhB, blB);            // prefetch V k=0 B-frags across the barrier
    __syncthreads();

    // ---- P2v: V GEMM. C[25,256] -> plane0 (Q dead), unswizzled ----
    {
        f32x4 acc[2][2];
        #pragma unroll
        for (int mt = 0; mt < 2; ++mt)
            #pragma unroll
            for (int nt = 0; nt < 2; ++nt) acc[mt][nt] = (f32x4)0.f;
        run_gemm(loadA, loadB_v, bhB, blB, acc);
        store_c(acc, bv[wid * 32 + lm], bv[wid * 32 + 16 + lm], plane0, false, false);
    }
    __syncthreads();

    // ---- P5: att = w @ V (f32), write split-bf16 into hs ----
    {
        const int h1 = (tid >> 5) & 7, hd = tid & 31;   // col = d
        #pragma unroll
        for (int i = 0; i < 13; ++i) {
            if (i >= gn) break;
            const int g = g0 + i;
            float a = 0.f;
            #pragma unroll
            for (int h2 = 0; h2 < NH; ++h2)
                a += plane1[g * 64 + h1 * 8 + h2] * plane0[g * SQ + h2 * NHD + hd];
            u16 h, l; splitf(a, h, l);
            hs_hi[g * SB + d] = h; hs_lo[g * SB + d] = l;
        }
    }
    loadB_wo(0, bhB, blB);           // prefetch Wo k=0 B-frags across the barrier
    __syncthreads();

    // ---- P6: Wo GEMM. C[25,256] -> plane1 (ss dead) ----
    {
        f32x4 acc[2][2];
        #pragma unroll
        for (int mt = 0; mt < 2; ++mt)
            #pragma unroll
            for (int nt = 0; nt < 2; ++nt) acc[mt][nt] = (f32x4)0.f;
        run_gemm(loadA, loadB_wo, bhB, blB, acc);
        store_c(acc, bo[wid * 32 + lm], bo[wid * 32 + 16 + lm], plane1, false, false);
    }
    __syncthreads();

    // ---- P7: norm1; x residual re-read from global (L2/L3-hot); x1 -> hs split-bf16 ----
    {
        float zv[13];
        #pragma unroll
        for (int i = 0; i < 13; ++i) {
            if (i >= gn) break;
            zv[i] = plane1[(g0 + i) * SQ + d] + x[base + (g0 + i) * ND + d];
        }
        norm_stats8(zv, gn, lane, wid, tid, s_wred, s_mu, s_rsd);
        #pragma unroll
        for (int i = 0; i < 13; ++i) {
            if (i >= gn) break;
            const float x1 = af * (zv[i] - s_mu[g0 + i]) * s_rsd[g0 + i] + bef;
            u16 h, l; splitf(x1, h, l);
            hs_hi[(g0 + i) * SB + d] = h; hs_lo[(g0 + i) * SB + d] = l;
        }
    }
    loadB_wfc(0, bhB, blB);          // prefetch Wfc k=0 B-frags across the barrier
    __syncthreads();

    // ---- P8: Wfc GEMM; epilogue relu(acc+bfc) -> plane1 ----
    {
        f32x4 acc[2][2];
        #pragma unroll
        for (int mt = 0; mt < 2; ++mt)
            #pragma unroll
            for (int nt = 0; nt < 2; ++nt) acc[mt][nt] = (f32x4)0.f;
        run_gemm(loadA, loadB_wfc, bhB, blB, acc);
        store_c(acc, bfc[wid * 32 + lm], bfc[wid * 32 + 16 + lm], plane1, false, true);
    }
    __syncthreads();

    // ---- P9: norm2 -> out; x1 reconstructed from hs split-bf16 (err ~1e-7 rel) ----
    {
        float z2[13];
        #pragma unroll
        for (int i = 0; i < 13; ++i) {
            if (i >= gn) break;
            const int g = g0 + i;
            const float x1 = bf2f(hs_hi[g * SB + d]) + bf2f(hs_lo[g * SB + d]);
            z2[i] = x1 + plane1[g * SQ + d];
        }
        norm_stats8(z2, gn, lane, wid, tid, s_wred, s_mu, s_rsd);
        #pragma unroll
        for (int i = 0; i < 13; ++i) {
            if (i >= gn) break;
            out[base + (g0 + i) * ND + d] = af * (z2[i] - s_mu[g0 + i]) * s_rsd[g0 + i] + bef;
        }
    }
}

extern "C" void kernel_launch(void* const* d_in, const int* in_sizes, int n_in,
                              void* d_out, int out_size, void* d_ws, size_t ws_size,
                              hipStream_t stream) {
    (void)in_sizes; (void)n_in; (void)out_size;
    const float* x     = (const float*)d_in[0];
    const float* adj   = (const float*)d_in[1];
    const float* Wq    = (const float*)d_in[2];
    const float* bq    = (const float*)d_in[3];
    const float* Wk    = (const float*)d_in[4];
    const float* bk    = (const float*)d_in[5];
    const float* Wv    = (const float*)d_in[6];
    const float* bv    = (const float*)d_in[7];
    const float* Wo    = (const float*)d_in[8];
    const float* bo    = (const float*)d_in[9];
    const float* Wfc   = (const float*)d_in[10];
    const float* bfc   = (const float*)d_in[11];
    const float* alpha = (const float*)d_in[12];
    const float* beta  = (const float*)d_in[13];
    float* out = (float*)d_out;
    u16* ws = (u16*)d_ws;

    const bool prep = (ws_size >= WS_NEED_BYTES);

    hipFuncSetAttribute((const void*)enc_mfma<true>,
                        hipFuncAttributeMaxDynamicSharedMemorySize, SMEM_TOT);
    hipFuncSetAttribute((const void*)enc_mfma<false>,
                        hipFuncAttributeMaxDynamicSharedMemorySize, SMEM_TOT);

    if (prep) {
        prep_w<<<dim3(1280), dim3(256), 0, stream>>>(Wq, Wk, Wv, Wo, Wfc, ws);
        enc_mfma<true><<<dim3(NB * NT), dim3(NTH), SMEM_TOT, stream>>>(
            x, adj, Wq, bq, Wk, bk, Wv, bv, Wo, bo, Wfc, bfc, alpha, beta, out, ws);
    } else {
        enc_mfma<false><<<dim3(NB * NT), dim3(NTH), SMEM_TOT, stream>>>(
            x, adj, Wq, bq, Wk, bk, Wv, bv, Wo, bo, Wfc, bfc, alpha, beta, out, ws);
    }
}

// Round 5
// 863.758 us; speedup vs baseline: 1.6967x; 1.1478x over previous
//
#include <hip/hip_runtime.h>

#define NB 32
#define NT 120
#define NG 25
#define ND 256
#define NH 8
#define NHD 32
#define NTH 512

typedef unsigned short u16;
typedef unsigned int u32;

typedef __bf16 bf16x8 __attribute__((ext_vector_type(8)));
typedef float  f32x4  __attribute__((ext_vector_type(4)));

// ---- LDS layout (dynamic, 80448 B; 2 blocks/CU) ----
// hs    : split-bf16 A operand, 25 rows (h -> att -> x1), masked frag loads
// plane0: adj (P0-P1) | Q swz (P2q-P3) | V (P2v-P5) | x1 f32 (P7-P9)
// plane1: K swz (P2k-P3) | ss [25][64] (P4-P5) | z (P6-P7) | fc (P8-P9)
// s_sm  : softmax scratch (P4) | wred/mu/rsd (P7,P9) -- time-disjoint
#define SB 264                    // u16 row stride for hs
#define SQ 260                    // f32 row stride for planes
#define OFF_HS_HI 0               // u16[25*264] = 13200 B
#define OFF_HS_LO 13200
#define OFF_P0    26400           // f32[25*260] = 26000 B
#define OFF_P1    52400           // f32[25*260] = 26000 B
#define OFF_SM    78400           // f32[8][64]  = 2048 B
#define SMEM_TOT  80448
#define OFF_WRED  78400           // f32[8][13][2] = 832 (aliases s_sm; disjoint in time)
#define OFF_MU    79232           // f32[25]
#define OFF_RSD   79336           // f32[25]  (ends 79436 <= 80448)

// ---- ws split-weight plane offsets (u16 elements) ----
#define WS_QKV_HI 0
#define WS_QKV_LO 196608
#define WS_WO_HI  393216
#define WS_WO_LO  458752
#define WS_WFC_HI 524288
#define WS_WFC_LO 589824
#define WS_NEED_BYTES (655360ull * 2ull)   // 1,310,720 B

__device__ __forceinline__ float bf2f(u16 u) { return __uint_as_float(((u32)u) << 16); }
__device__ __forceinline__ u16 f2bf(float f) {   // round-to-nearest-even
    u32 x = __float_as_uint(f);
    return (u16)((x + 0x7FFFu + ((x >> 16) & 1u)) >> 16);
}
__device__ __forceinline__ void splitf(float v, u16& h, u16& l) {
    h = f2bf(v);
    l = f2bf(v - bf2f(h));   // residual ~2^-18 rel
}
__device__ __forceinline__ bf16x8 ld_bf8(const u16* p) {   // p 16B-aligned
    uint4 u = *(const uint4*)p;
    return __builtin_bit_cast(bf16x8, u);
}
__device__ __forceinline__ bf16x8 zero_bf8() {
    uint4 z{0u, 0u, 0u, 0u};
    return __builtin_bit_cast(bf16x8, z);
}

// Build split-weight workspace: hi/lo bf16 planes, row-major [rows][256].
__global__ __launch_bounds__(256)
void prep_w(const float* __restrict__ Wq, const float* __restrict__ Wk,
            const float* __restrict__ Wv, const float* __restrict__ Wo,
            const float* __restrict__ Wfc, u16* __restrict__ ws) {
    int e = blockIdx.x * 256 + threadIdx.x;     // 0 .. 327679
    float v; int hi_base, lo_base, idx;
    if (e < 196608) {                            // stacked Q,K,V rows 0..767
        int n = e >> 8, k = e & 255;
        const float* W = (n < 256) ? Wq : (n < 512 ? Wk : Wv);
        v = W[(n & 255) * 256 + k];
        hi_base = WS_QKV_HI; lo_base = WS_QKV_LO; idx = e;
    } else if (e < 262144) {
        idx = e - 196608; v = Wo[idx];
        hi_base = WS_WO_HI; lo_base = WS_WO_LO;
    } else {
        idx = e - 262144; v = Wfc[idx];
        hi_base = WS_WFC_HI; lo_base = WS_WFC_LO;
    }
    u16 h, l; splitf(v, h, l);
    ws[hi_base + idx] = h;
    ws[lo_base + idx] = l;
}

// 512-thread norm stats: waves 0-3 hold g 0-12 (rep 0), waves 4-7 g 13-24.
__device__ __forceinline__ void norm_stats8(const float* zv, int gn,
                                            int lane, int wid, int tid,
                                            float (*s_wred)[13][2], float* s_mu, float* s_rsd) {
    #pragma unroll
    for (int i = 0; i < 13; ++i) {
        if (i >= gn) break;
        float s = zv[i], q = zv[i] * zv[i];
        #pragma unroll
        for (int off = 32; off > 0; off >>= 1) {
            s += __shfl_xor(s, off, 64);
            q += __shfl_xor(q, off, 64);
        }
        if (lane == 0) { s_wred[wid][i][0] = s; s_wred[wid][i][1] = q; }
    }
    __syncthreads();
    if (tid < NG) {
        const int g = tid;
        const int wb = (g < 13) ? 0 : 4, lg = (g < 13) ? g : g - 13;
        float s = 0.f, q = 0.f;
        #pragma unroll
        for (int w = 0; w < 4; ++w) { s += s_wred[wb + w][lg][0]; q += s_wred[wb + w][lg][1]; }
        float mu = s * (1.f / 256.f);
        float var = fmaxf((q - 256.f * mu * mu) * (1.f / 255.f), 0.f);  // ddof=1
        s_mu[g] = mu;
        s_rsd[g] = 1.f / (sqrtf(var) + 1e-6f);
    }
    __syncthreads();
}

// B-fragment: rows of row-major [rows][256] weights (split planes in ws, or inline f32).
template<bool PREP>
__device__ __forceinline__ void load_bfrag(const u16* wshi, const u16* wslo,
                                           const float* Wf, int row, int koff,
                                           bf16x8& bh, bf16x8& bl) {
    if constexpr (PREP) {
        const int off = row * 256 + koff;
        bh = ld_bf8(wshi + off);
        bl = ld_bf8(wslo + off);
    } else {
        const float* p = Wf + row * 256 + koff;
        float4 w0 = *(const float4*)p, w1 = *(const float4*)(p + 4);
        float wv[8] = {w0.x, w0.y, w0.z, w0.w, w1.x, w1.y, w1.z, w1.w};
        union { u16 s[8]; bf16x8 v; } H, L;
        #pragma unroll
        for (int j = 0; j < 8; ++j) splitf(wv[j], H.s[j], L.s[j]);
        bh = H.v; bl = L.v;
    }
}

// Lean single-buffered GEMM: 2 B-tiles/wave, 8 K-steps.
// Caller preloads bh/bl for k=0; B loads issue first each step (VMEM latency
// overlaps the LDS A-reads and prior MFMAs); acc must be zero-initialized.
template<typename FA, typename FB>
__device__ __forceinline__ void run_gemm(FA&& ldA, FB&& ldB,
                                         bf16x8 (&bh)[2], bf16x8 (&bl)[2],
                                         f32x4 (&acc)[2][2]) {
    bf16x8 ah[2], al[2];
    #pragma unroll
    for (int ki = 0; ki < 8; ++ki) {
        if (ki) ldB(32 * ki, bh, bl);
        ldA(32 * ki, ah, al);
        #pragma unroll
        for (int j = 0; j < 2; ++j)
            #pragma unroll
            for (int mt = 0; mt < 2; ++mt)
                acc[mt][j] = __builtin_amdgcn_mfma_f32_16x16x32_bf16(ah[mt], bh[j], acc[mt][j], 0, 0, 0);
        #pragma unroll
        for (int j = 0; j < 2; ++j)
            #pragma unroll
            for (int mt = 0; mt < 2; ++mt)
                acc[mt][j] = __builtin_amdgcn_mfma_f32_16x16x32_bf16(al[mt], bh[j], acc[mt][j], 0, 0, 0);
        #pragma unroll
        for (int j = 0; j < 2; ++j)
            #pragma unroll
            for (int mt = 0; mt < 2; ++mt)
                acc[mt][j] = __builtin_amdgcn_mfma_f32_16x16x32_bf16(ah[mt], bl[j], acc[mt][j], 0, 0, 0);
    }
}

template<bool PREP>
__global__ __launch_bounds__(NTH, 4)
void enc_mfma(const float* __restrict__ x,  const float* __restrict__ adj,
              const float* __restrict__ Wq, const float* __restrict__ bq,
              const float* __restrict__ Wk, const float* __restrict__ bk,
              const float* __restrict__ Wv, const float* __restrict__ bv,
              const float* __restrict__ Wo, const float* __restrict__ bo,
              const float* __restrict__ Wfc,const float* __restrict__ bfc,
              const float* __restrict__ alpha, const float* __restrict__ beta,
              float* __restrict__ out, const u16* __restrict__ ws)
{
    extern __shared__ char smem[];
    u16*   hs_hi  = (u16*)(smem + OFF_HS_HI);
    u16*   hs_lo  = (u16*)(smem + OFF_HS_LO);
    float* plane0 = (float*)(smem + OFF_P0);
    float* plane1 = (float*)(smem + OFF_P1);
    float* s_sm   = (float*)(smem + OFF_SM);
    float (*s_wred)[13][2] = (float(*)[13][2])(smem + OFF_WRED);
    float* s_mu  = (float*)(smem + OFF_MU);
    float* s_rsd = (float*)(smem + OFF_RSD);

    const int bt = blockIdx.x;
    const int tid = threadIdx.x;
    const int d = tid & 255, rep = tid >> 8;
    const int lane = tid & 63, wid = tid >> 6;          // wave id 0-7
    const int lm = lane & 15, quad = lane >> 4;
    const int g0 = rep ? 13 : 0, gn = rep ? 12 : 13;
    const long base = (long)bt * (NG * ND);

    // ---- fragment load helpers ----
    // A tile rows: mt=0 -> rows 0..15 (valid), mt=1 -> rows 16..31; rows >= 25 zero.
    auto loadA = [&](int k0, bf16x8 (&ah)[2], bf16x8 (&al)[2]) {
        const int koff = k0 + quad * 8;
        ah[0] = ld_bf8(hs_hi + lm * SB + koff);
        al[0] = ld_bf8(hs_lo + lm * SB + koff);
        if (lm < 9) {
            ah[1] = ld_bf8(hs_hi + (16 + lm) * SB + koff);
            al[1] = ld_bf8(hs_lo + (16 + lm) * SB + koff);
        } else {
            ah[1] = zero_bf8();
            al[1] = zero_bf8();
        }
    };
    // 2-tile B loads: rows wid*32 + j*16 + lm of each weight matrix.
    auto loadB_q = [&](int k0, bf16x8 (&bh)[2], bf16x8 (&bl)[2]) {
        const int koff = k0 + quad * 8;
        #pragma unroll
        for (int j = 0; j < 2; ++j)
            load_bfrag<PREP>(ws + WS_QKV_HI, ws + WS_QKV_LO, Wq,
                             wid * 32 + j * 16 + lm, koff, bh[j], bl[j]);
    };
    auto loadB_k = [&](int k0, bf16x8 (&bh)[2], bf16x8 (&bl)[2]) {
        const int koff = k0 + quad * 8;
        #pragma unroll
        for (int j = 0; j < 2; ++j)
            load_bfrag<PREP>(ws + WS_QKV_HI, ws + WS_QKV_LO, Wk,
                             PREP ? (256 + wid * 32 + j * 16 + lm) : (wid * 32 + j * 16 + lm),
                             koff, bh[j], bl[j]);
    };
    auto loadB_v = [&](int k0, bf16x8 (&bh)[2], bf16x8 (&bl)[2]) {
        const int koff = k0 + quad * 8;
        #pragma unroll
        for (int j = 0; j < 2; ++j)
            load_bfrag<PREP>(ws + WS_QKV_HI, ws + WS_QKV_LO, Wv,
                             PREP ? (512 + wid * 32 + j * 16 + lm) : (wid * 32 + j * 16 + lm),
                             koff, bh[j], bl[j]);
    };
    auto loadB_wo = [&](int k0, bf16x8 (&bh)[2], bf16x8 (&bl)[2]) {
        const int koff = k0 + quad * 8;
        #pragma unroll
        for (int j = 0; j < 2; ++j)
            load_bfrag<PREP>(ws + WS_WO_HI, ws + WS_WO_LO, Wo,
                             wid * 32 + j * 16 + lm, koff, bh[j], bl[j]);
    };
    auto loadB_wfc = [&](int k0, bf16x8 (&bh)[2], bf16x8 (&bl)[2]) {
        const int koff = k0 + quad * 8;
        #pragma unroll
        for (int j = 0; j < 2; ++j)
            load_bfrag<PREP>(ws + WS_WFC_HI, ws + WS_WFC_LO, Wfc,
                             wid * 32 + j * 16 + lm, koff, bh[j], bl[j]);
    };
    // Epilogue store: rows < 25 of C[25,256] into plane, optional swizzle / relu.
    auto store_c = [&](f32x4 (&acc)[2][2], float b0, float b1,
                       float* plane, bool swz, bool relu) {
        float bbv[2] = { b0, b1 };
        #pragma unroll
        for (int nt = 0; nt < 2; ++nt) {
            const int col = wid * 32 + nt * 16 + lm;
            const int pcol = swz ? (col ^ ((col >> 3) & 0x1C)) : col;
            #pragma unroll
            for (int mt = 0; mt < 2; ++mt)
                #pragma unroll
                for (int i = 0; i < 4; ++i) {
                    const int r = mt * 16 + quad * 4 + i;
                    if (mt == 0 || r < 25) {
                        float v = acc[mt][nt][i] + bbv[nt];
                        if (relu) v = fmaxf(v, 0.f);
                        plane[r * SQ + pcol] = v;
                    }
                }
        }
    };

    // single-buffer fragment registers (slot preloaded before each GEMM's barrier)
    bf16x8 bhB[2], blB[2];           // shared across GEMM phases (lifetimes disjoint)

    // ---- P0: stage adjacency into plane0; prefetch alpha/beta ----
    for (int i = tid; i < NG * NG; i += NTH) plane0[i] = adj[i];
    const float af = alpha[d], bef = beta[d];
    __syncthreads();

    // ---- P1: h = adj @ x (VALU, f32), write split-bf16 (25 rows) ----
    {
        float acc[13];
        #pragma unroll
        for (int i = 0; i < 13; ++i) acc[i] = 0.f;
        #pragma unroll
        for (int n = 0; n < NG; ++n) {
            float xv = x[base + n * ND + d];
            #pragma unroll
            for (int i = 0; i < 13; ++i)
                acc[i] += plane0[(g0 + i) * NG + n] * xv;  // i==12,rep1 reads in-bounds scratch; never stored
        }
        #pragma unroll
        for (int i = 0; i < 13; ++i) {
            if (i >= gn) break;
            u16 h, l; splitf(acc[i], h, l);
            hs_hi[(g0 + i) * SB + d] = h; hs_lo[(g0 + i) * SB + d] = l;
        }
    }
    loadB_q(0, bhB, blB);            // prefetch Q k=0 B-frags across the barrier
    __syncthreads();

    // ---- P2q: Q GEMM. C[25,256] -> plane0 swizzled (adj dead after barrier) ----
    {
        f32x4 acc[2][2];
        #pragma unroll
        for (int mt = 0; mt < 2; ++mt)
            #pragma unroll
            for (int nt = 0; nt < 2; ++nt) acc[mt][nt] = (f32x4)0.f;
        run_gemm(loadA, loadB_q, bhB, blB, acc);
        store_c(acc, bq[wid * 32 + lm], bq[wid * 32 + 16 + lm], plane0, true, false);
    }
    // ---- P2k: K GEMM. C[25,256] -> plane1 swizzled. (reads only stable hs/ws: no barrier) ----
    {
        f32x4 acc[2][2];
        #pragma unroll
        for (int mt = 0; mt < 2; ++mt)
            #pragma unroll
            for (int nt = 0; nt < 2; ++nt) acc[mt][nt] = (f32x4)0.f;
        loadB_k(0, bhB, blB);
        run_gemm(loadA, loadB_k, bhB, blB, acc);
        store_c(acc, bk[wid * 32 + lm], bk[wid * 32 + 16 + lm], plane1, true, false);
    }
    __syncthreads();

    // ---- P3: scores[g][h1][h2] = Q_g K_g^T / sqrt(32), kept in registers ----
    float sreg[4];
    {
        #pragma unroll
        for (int kk = 0; kk < 4; ++kk) {
            const int i = tid + kk * NTH;
            const int ii = (i < NG * 64) ? i : 0;        // lanes past 1600 compute a dummy
            const int g = ii >> 6, hh = ii & 63;
            const int jq = hh >> 3, jk = hh & 7;
            const float4* q4 = (const float4*)(plane0 + g * SQ + jq * 32);
            const float4* k4 = (const float4*)(plane1 + g * SQ + jk * 32);
            float s = 0.f;
            #pragma unroll
            for (int c = 0; c < 8; ++c) {
                float4 qa = q4[c ^ jq], ka = k4[c ^ jk];  // unswizzle on read
                s += qa.x * ka.x + qa.y * ka.y + qa.z * ka.z + qa.w * ka.w;
            }
            sreg[kk] = s * 0.17677669529663687f;
        }
    }
    __syncthreads();   // Q,K dead; plane1 reusable for ss

    // ---- P4: softmax over g (dim=1); thread owns g = part+8k at fixed col ----
    {
        const int col = tid & 63, part = tid >> 6;
        float m = -1e30f;
        #pragma unroll
        for (int kk = 0; kk < 4; ++kk)
            if (tid + kk * NTH < NG * 64) m = fmaxf(m, sreg[kk]);
        s_sm[part * 64 + col] = m;
        __syncthreads();
        float cm = -1e30f;
        #pragma unroll
        for (int p = 0; p < 8; ++p) cm = fmaxf(cm, s_sm[p * 64 + col]);
        __syncthreads();                          // all reads done before overwrite
        float den = 0.f;
        #pragma unroll
        for (int kk = 0; kk < 4; ++kk)
            if (tid + kk * NTH < NG * 64) {
                float e = expf(sreg[kk] - cm);
                sreg[kk] = e;
                den += e;
            }
        s_sm[part * 64 + col] = den;
        __syncthreads();
        float tden = 0.f;
        #pragma unroll
        for (int p = 0; p < 8; ++p) tden += s_sm[p * 64 + col];
        const float inv = 1.f / tden;
        #pragma unroll
        for (int kk = 0; kk < 4; ++kk) {
            const int i = tid + kk * NTH;
            if (i < NG * 64) plane1[i] = sreg[kk] * inv;   // ss -> K region
        }
    }
    loadB_v(0, bhB, blB);            // prefetch V k=0 B-frags across the barrier
    __syncthreads();

    // ---- P2v: V GEMM. C[25,256] -> plane0 (Q dead), unswizzled ----
    {
        f32x4 acc[2][2];
        #pragma unroll
        for (int mt = 0; mt < 2; ++mt)
            #pragma unroll
            for (int nt = 0; nt < 2; ++nt) acc[mt][nt] = (f32x4)0.f;
        run_gemm(loadA, loadB_v, bhB, blB, acc);
        store_c(acc, bv[wid * 32 + lm], bv[wid * 32 + 16 + lm], plane0, false, false);
    }
    __syncthreads();

    // ---- P5: att = w @ V (f32), write split-bf16 into hs ----
    {
        const int h1 = (tid >> 5) & 7, hd = tid & 31;   // col = d
        #pragma unroll
        for (int i = 0; i < 13; ++i) {
            if (i >= gn) break;
            const int g = g0 + i;
            float a = 0.f;
            #pragma unroll
            for (int h2 = 0; h2 < NH; ++h2)
                a += plane1[g * 64 + h1 * 8 + h2] * plane0[g * SQ + h2 * NHD + hd];
            u16 h, l; splitf(a, h, l);
            hs_hi[g * SB + d] = h; hs_lo[g * SB + d] = l;
        }
    }
    loadB_wo(0, bhB, blB);           // prefetch Wo k=0 B-frags across the barrier
    __syncthreads();

    // ---- P6: Wo GEMM. C[25,256] -> plane1 (ss dead) ----
    {
        f32x4 acc[2][2];
        #pragma unroll
        for (int mt = 0; mt < 2; ++mt)
            #pragma unroll
            for (int nt = 0; nt < 2; ++nt) acc[mt][nt] = (f32x4)0.f;
        run_gemm(loadA, loadB_wo, bhB, blB, acc);
        store_c(acc, bo[wid * 32 + lm], bo[wid * 32 + 16 + lm], plane1, false, false);
    }
    __syncthreads();

    // ---- P7: norm1; x residual re-read from global (L2/L3-hot);
    //      x1 -> hs split-bf16 (P8 A-operand) AND plane0 f32 (exact, for P9) ----
    {
        float zv[13];
        #pragma unroll
        for (int i = 0; i < 13; ++i) {
            if (i >= gn) break;
            zv[i] = plane1[(g0 + i) * SQ + d] + x[base + (g0 + i) * ND + d];
        }
        norm_stats8(zv, gn, lane, wid, tid, s_wred, s_mu, s_rsd);
        #pragma unroll
        for (int i = 0; i < 13; ++i) {
            if (i >= gn) break;
            const float x1 = af * (zv[i] - s_mu[g0 + i]) * s_rsd[g0 + i] + bef;
            u16 h, l; splitf(x1, h, l);
            hs_hi[(g0 + i) * SB + d] = h; hs_lo[(g0 + i) * SB + d] = l;
            plane0[(g0 + i) * SQ + d] = x1;          // V dead; exact copy for P9
        }
    }
    loadB_wfc(0, bhB, blB);          // prefetch Wfc k=0 B-frags across the barrier
    __syncthreads();

    // ---- P8: Wfc GEMM; epilogue relu(acc+bfc) -> plane1 ----
    {
        f32x4 acc[2][2];
        #pragma unroll
        for (int mt = 0; mt < 2; ++mt)
            #pragma unroll
            for (int nt = 0; nt < 2; ++nt) acc[mt][nt] = (f32x4)0.f;
        run_gemm(loadA, loadB_wfc, bhB, blB, acc);
        store_c(acc, bfc[wid * 32 + lm], bfc[wid * 32 + 16 + lm], plane1, false, true);
    }
    __syncthreads();

    // ---- P9: norm2 -> out; x1 exact from plane0 ----
    {
        float z2[13];
        #pragma unroll
        for (int i = 0; i < 13; ++i) {
            if (i >= gn) break;
            const int g = g0 + i;
            z2[i] = plane0[g * SQ + d] + plane1[g * SQ + d];
        }
        norm_stats8(z2, gn, lane, wid, tid, s_wred, s_mu, s_rsd);
        #pragma unroll
        for (int i = 0; i < 13; ++i) {
            if (i >= gn) break;
            out[base + (g0 + i) * ND + d] = af * (z2[i] - s_mu[g0 + i]) * s_rsd[g0 + i] + bef;
        }
    }
}

extern "C" void kernel_launch(void* const* d_in, const int* in_sizes, int n_in,
                              void* d_out, int out_size, void* d_ws, size_t ws_size,
                              hipStream_t stream) {
    (void)in_sizes; (void)n_in; (void)out_size;
    const float* x     = (const float*)d_in[0];
    const float* adj   = (const float*)d_in[1];
    const float* Wq    = (const float*)d_in[2];
    const float* bq    = (const float*)d_in[3];
    const float* Wk    = (const float*)d_in[4];
    const float* bk    = (const float*)d_in[5];
    const float* Wv    = (const float*)d_in[6];
    const float* bv    = (const float*)d_in[7];
    const float* Wo    = (const float*)d_in[8];
    const float* bo    = (const float*)d_in[9];
    const float* Wfc   = (const float*)d_in[10];
    const float* bfc   = (const float*)d_in[11];
    const float* alpha = (const float*)d_in[12];
    const float* beta  = (const float*)d_in[13];
    float* out = (float*)d_out;
    u16* ws = (u16*)d_ws;

    const bool prep = (ws_size >= WS_NEED_BYTES);

    hipFuncSetAttribute((const void*)enc_mfma<true>,
                        hipFuncAttributeMaxDynamicSharedMemorySize, SMEM_TOT);
    hipFuncSetAttribute((const void*)enc_mfma<false>,
                        hipFuncAttributeMaxDynamicSharedMemorySize, SMEM_TOT);

    if (prep) {
        prep_w<<<dim3(1280), dim3(256), 0, stream>>>(Wq, Wk, Wv, Wo, Wfc, ws);
        enc_mfma<true><<<dim3(NB * NT), dim3(NTH), SMEM_TOT, stream>>>(
            x, adj, Wq, bq, Wk, bk, Wv, bv, Wo, bo, Wfc, bfc, alpha, beta, out, ws);
    } else {
        enc_mfma<false><<<dim3(NB * NT), dim3(NTH), SMEM_TOT, stream>>>(
            x, adj, Wq, bq, Wk, bk, Wv, bv, Wo, bo, Wfc, bfc, alpha, beta, out, ws);
    }
}

// Round 6
// 863.633 us; speedup vs baseline: 1.6969x; 1.0001x over previous
//
#include <hip/hip_runtime.h>

#define NB 32
#define NT 120
#define NG 25
#define ND 256
#define NH 8
#define NHD 32
#define NTH 512

typedef unsigned short u16;
typedef unsigned int u32;

typedef __bf16 bf16x8 __attribute__((ext_vector_type(8)));
typedef float  f32x4  __attribute__((ext_vector_type(4)));

// ---- LDS layout (dynamic, 80448 B; 2 blocks/CU needs arch+AGPR <= 128) ----
// hs    : split-bf16 A operand, 25 rows (h -> att -> x1), masked frag loads
// plane0: adj (P0-P1) | Q swz (P2qk-P3) | V (P2v-P5) | x1 f32 (P7-P9)
// plane1: K swz (P2qk-P3) | ss [25][64] (P4-P5) | z (P6-P7) | fc (P8-P9)
// s_sm  : softmax scratch (P4) | wred/mu/rsd (P7,P9) -- time-disjoint
#define SB 264                    // u16 row stride for hs
#define SQ 260                    // f32 row stride for planes
#define OFF_HS_HI 0               // u16[25*264] = 13200 B
#define OFF_HS_LO 13200
#define OFF_P0    26400           // f32[25*260] = 26000 B
#define OFF_P1    52400           // f32[25*260] = 26000 B
#define OFF_SM    78400           // f32[8][64]  = 2048 B
#define SMEM_TOT  80448
#define OFF_WRED  78400           // f32[8][13][2] = 832 (aliases s_sm; disjoint in time)
#define OFF_MU    79232           // f32[25]
#define OFF_RSD   79336           // f32[25]  (ends 79436 <= 80448)

// ---- ws split-weight plane offsets (u16 elements) ----
#define WS_QKV_HI 0
#define WS_QKV_LO 196608
#define WS_WO_HI  393216
#define WS_WO_LO  458752
#define WS_WFC_HI 524288
#define WS_WFC_LO 589824
#define WS_NEED_BYTES (655360ull * 2ull)   // 1,310,720 B

__device__ __forceinline__ float bf2f(u16 u) { return __uint_as_float(((u32)u) << 16); }
__device__ __forceinline__ u16 f2bf(float f) {   // round-to-nearest-even
    u32 x = __float_as_uint(f);
    return (u16)((x + 0x7FFFu + ((x >> 16) & 1u)) >> 16);
}
__device__ __forceinline__ void splitf(float v, u16& h, u16& l) {
    h = f2bf(v);
    l = f2bf(v - bf2f(h));   // residual ~2^-18 rel
}
__device__ __forceinline__ bf16x8 ld_bf8(const u16* p) {   // p 16B-aligned
    uint4 u = *(const uint4*)p;
    return __builtin_bit_cast(bf16x8, u);
}
__device__ __forceinline__ bf16x8 zero_bf8() {
    uint4 z{0u, 0u, 0u, 0u};
    return __builtin_bit_cast(bf16x8, z);
}

// Build split-weight workspace: hi/lo bf16 planes, row-major [rows][256].
__global__ __launch_bounds__(256)
void prep_w(const float* __restrict__ Wq, const float* __restrict__ Wk,
            const float* __restrict__ Wv, const float* __restrict__ Wo,
            const float* __restrict__ Wfc, u16* __restrict__ ws) {
    int e = blockIdx.x * 256 + threadIdx.x;     // 0 .. 327679
    float v; int hi_base, lo_base, idx;
    if (e < 196608) {                            // stacked Q,K,V rows 0..767
        int n = e >> 8, k = e & 255;
        const float* W = (n < 256) ? Wq : (n < 512 ? Wk : Wv);
        v = W[(n & 255) * 256 + k];
        hi_base = WS_QKV_HI; lo_base = WS_QKV_LO; idx = e;
    } else if (e < 262144) {
        idx = e - 196608; v = Wo[idx];
        hi_base = WS_WO_HI; lo_base = WS_WO_LO;
    } else {
        idx = e - 262144; v = Wfc[idx];
        hi_base = WS_WFC_HI; lo_base = WS_WFC_LO;
    }
    u16 h, l; splitf(v, h, l);
    ws[hi_base + idx] = h;
    ws[lo_base + idx] = l;
}

// 512-thread norm stats: waves 0-3 hold g 0-12 (rep 0), waves 4-7 g 13-24.
__device__ __forceinline__ void norm_stats8(const float* zv, int gn,
                                            int lane, int wid, int tid,
                                            float (*s_wred)[13][2], float* s_mu, float* s_rsd) {
    #pragma unroll
    for (int i = 0; i < 13; ++i) {
        if (i >= gn) break;
        float s = zv[i], q = zv[i] * zv[i];
        #pragma unroll
        for (int off = 32; off > 0; off >>= 1) {
            s += __shfl_xor(s, off, 64);
            q += __shfl_xor(q, off, 64);
        }
        if (lane == 0) { s_wred[wid][i][0] = s; s_wred[wid][i][1] = q; }
    }
    __syncthreads();
    if (tid < NG) {
        const int g = tid;
        const int wb = (g < 13) ? 0 : 4, lg = (g < 13) ? g : g - 13;
        float s = 0.f, q = 0.f;
        #pragma unroll
        for (int w = 0; w < 4; ++w) { s += s_wred[wb + w][lg][0]; q += s_wred[wb + w][lg][1]; }
        float mu = s * (1.f / 256.f);
        float var = fmaxf((q - 256.f * mu * mu) * (1.f / 255.f), 0.f);  // ddof=1
        s_mu[g] = mu;
        s_rsd[g] = 1.f / (sqrtf(var) + 1e-6f);
    }
    __syncthreads();
}

// B-fragment: rows of row-major [rows][256] weights (split planes in ws, or inline f32).
template<bool PREP>
__device__ __forceinline__ void load_bfrag(const u16* wshi, const u16* wslo,
                                           const float* Wf, int row, int koff,
                                           bf16x8& bh, bf16x8& bl) {
    if constexpr (PREP) {
        const int off = row * 256 + koff;
        bh = ld_bf8(wshi + off);
        bl = ld_bf8(wslo + off);
    } else {
        const float* p = Wf + row * 256 + koff;
        float4 w0 = *(const float4*)p, w1 = *(const float4*)(p + 4);
        float wv[8] = {w0.x, w0.y, w0.z, w0.w, w1.x, w1.y, w1.z, w1.w};
        union { u16 s[8]; bf16x8 v; } H, L;
        #pragma unroll
        for (int j = 0; j < 8; ++j) splitf(wv[j], H.s[j], L.s[j]);
        bh = H.v; bl = L.v;
    }
}

// Lean single-buffered GEMM: 2 B-tiles/wave, 8 K-steps.
// Caller preloads bh/bl for k=0; B loads issue first each step (VMEM latency
// overlaps the LDS A-reads and prior MFMAs); acc must be zero-initialized.
template<typename FA, typename FB>
__device__ __forceinline__ void run_gemm(FA&& ldA, FB&& ldB,
                                         bf16x8 (&bh)[2], bf16x8 (&bl)[2],
                                         f32x4 (&acc)[2][2]) {
    bf16x8 ah[2], al[2];
    #pragma unroll
    for (int ki = 0; ki < 8; ++ki) {
        if (ki) ldB(32 * ki, bh, bl);
        ldA(32 * ki, ah, al);
        __builtin_amdgcn_s_setprio(1);
        #pragma unroll
        for (int j = 0; j < 2; ++j)
            #pragma unroll
            for (int mt = 0; mt < 2; ++mt)
                acc[mt][j] = __builtin_amdgcn_mfma_f32_16x16x32_bf16(ah[mt], bh[j], acc[mt][j], 0, 0, 0);
        #pragma unroll
        for (int j = 0; j < 2; ++j)
            #pragma unroll
            for (int mt = 0; mt < 2; ++mt)
                acc[mt][j] = __builtin_amdgcn_mfma_f32_16x16x32_bf16(al[mt], bh[j], acc[mt][j], 0, 0, 0);
        #pragma unroll
        for (int j = 0; j < 2; ++j)
            #pragma unroll
            for (int mt = 0; mt < 2; ++mt)
                acc[mt][j] = __builtin_amdgcn_mfma_f32_16x16x32_bf16(ah[mt], bl[j], acc[mt][j], 0, 0, 0);
        __builtin_amdgcn_s_setprio(0);
    }
}

template<bool PREP>
__global__ __launch_bounds__(NTH, 4)
void enc_mfma(const float* __restrict__ x,  const float* __restrict__ adj,
              const float* __restrict__ Wq, const float* __restrict__ bq,
              const float* __restrict__ Wk, const float* __restrict__ bk,
              const float* __restrict__ Wv, const float* __restrict__ bv,
              const float* __restrict__ Wo, const float* __restrict__ bo,
              const float* __restrict__ Wfc,const float* __restrict__ bfc,
              const float* __restrict__ alpha, const float* __restrict__ beta,
              float* __restrict__ out, const u16* __restrict__ ws)
{
    extern __shared__ char smem[];
    u16*   hs_hi  = (u16*)(smem + OFF_HS_HI);
    u16*   hs_lo  = (u16*)(smem + OFF_HS_LO);
    float* plane0 = (float*)(smem + OFF_P0);
    float* plane1 = (float*)(smem + OFF_P1);
    float* s_sm   = (float*)(smem + OFF_SM);
    float (*s_wred)[13][2] = (float(*)[13][2])(smem + OFF_WRED);
    float* s_mu  = (float*)(smem + OFF_MU);
    float* s_rsd = (float*)(smem + OFF_RSD);

    const int bt = blockIdx.x;
    const int tid = threadIdx.x;
    const int d = tid & 255, rep = tid >> 8;
    const int lane = tid & 63, wid = tid >> 6;          // wave id 0-7
    const int lm = lane & 15, quad = lane >> 4;
    const int g0 = rep ? 13 : 0, gn = rep ? 12 : 13;
    const long base = (long)bt * (NG * ND);

    // ---- fragment load helpers ----
    // A tile rows: mt=0 -> rows 0..15 (valid), mt=1 -> rows 16..31; rows >= 25 zero.
    auto loadA = [&](int k0, bf16x8 (&ah)[2], bf16x8 (&al)[2]) {
        const int koff = k0 + quad * 8;
        ah[0] = ld_bf8(hs_hi + lm * SB + koff);
        al[0] = ld_bf8(hs_lo + lm * SB + koff);
        if (lm < 9) {
            ah[1] = ld_bf8(hs_hi + (16 + lm) * SB + koff);
            al[1] = ld_bf8(hs_lo + (16 + lm) * SB + koff);
        } else {
            ah[1] = zero_bf8();
            al[1] = zero_bf8();
        }
    };
    // 2-tile B loads: rows wid*32 + j*16 + lm of each weight matrix.
    auto loadB_q = [&](int k0, bf16x8 (&bh)[2], bf16x8 (&bl)[2]) {
        const int koff = k0 + quad * 8;
        #pragma unroll
        for (int j = 0; j < 2; ++j)
            load_bfrag<PREP>(ws + WS_QKV_HI, ws + WS_QKV_LO, Wq,
                             wid * 32 + j * 16 + lm, koff, bh[j], bl[j]);
    };
    auto loadB_k = [&](int k0, bf16x8 (&bh)[2], bf16x8 (&bl)[2]) {
        const int koff = k0 + quad * 8;
        #pragma unroll
        for (int j = 0; j < 2; ++j)
            load_bfrag<PREP>(ws + WS_QKV_HI, ws + WS_QKV_LO, Wk,
                             PREP ? (256 + wid * 32 + j * 16 + lm) : (wid * 32 + j * 16 + lm),
                             koff, bh[j], bl[j]);
    };
    auto loadB_v = [&](int k0, bf16x8 (&bh)[2], bf16x8 (&bl)[2]) {
        const int koff = k0 + quad * 8;
        #pragma unroll
        for (int j = 0; j < 2; ++j)
            load_bfrag<PREP>(ws + WS_QKV_HI, ws + WS_QKV_LO, Wv,
                             PREP ? (512 + wid * 32 + j * 16 + lm) : (wid * 32 + j * 16 + lm),
                             koff, bh[j], bl[j]);
    };
    auto loadB_wo = [&](int k0, bf16x8 (&bh)[2], bf16x8 (&bl)[2]) {
        const int koff = k0 + quad * 8;
        #pragma unroll
        for (int j = 0; j < 2; ++j)
            load_bfrag<PREP>(ws + WS_WO_HI, ws + WS_WO_LO, Wo,
                             wid * 32 + j * 16 + lm, koff, bh[j], bl[j]);
    };
    auto loadB_wfc = [&](int k0, bf16x8 (&bh)[2], bf16x8 (&bl)[2]) {
        const int koff = k0 + quad * 8;
        #pragma unroll
        for (int j = 0; j < 2; ++j)
            load_bfrag<PREP>(ws + WS_WFC_HI, ws + WS_WFC_LO, Wfc,
                             wid * 32 + j * 16 + lm, koff, bh[j], bl[j]);
    };
    // Epilogue store: rows < 25 of C[25,256] into plane, optional swizzle / relu.
    auto store_c = [&](f32x4 (&acc)[2][2], float b0, float b1,
                       float* plane, bool swz, bool relu) {
        float bbv[2] = { b0, b1 };
        #pragma unroll
        for (int nt = 0; nt < 2; ++nt) {
            const int col = wid * 32 + nt * 16 + lm;
            const int pcol = swz ? (col ^ ((col >> 3) & 0x1C)) : col;
            #pragma unroll
            for (int mt = 0; mt < 2; ++mt)
                #pragma unroll
                for (int i = 0; i < 4; ++i) {
                    const int r = mt * 16 + quad * 4 + i;
                    if (mt == 0 || r < 25) {
                        float v = acc[mt][nt][i] + bbv[nt];
                        if (relu) v = fmaxf(v, 0.f);
                        plane[r * SQ + pcol] = v;
                    }
                }
        }
    };

    // single-buffer fragment registers for V/Wo/Wfc GEMM phases
    bf16x8 bhB[2], blB[2];

    // ---- P0: stage adjacency into plane0; prefetch alpha/beta ----
    for (int i = tid; i < NG * NG; i += NTH) plane0[i] = adj[i];
    const float af = alpha[d], bef = beta[d];
    __syncthreads();

    // ---- P1: h = adj @ x (VALU, f32), write split-bf16 (25 rows) ----
    {
        float acc[13];
        #pragma unroll
        for (int i = 0; i < 13; ++i) acc[i] = 0.f;
        #pragma unroll
        for (int n = 0; n < NG; ++n) {
            float xv = x[base + n * ND + d];
            #pragma unroll
            for (int i = 0; i < 13; ++i)
                acc[i] += plane0[(g0 + i) * NG + n] * xv;  // i==12,rep1 reads in-bounds scratch; never stored
        }
        #pragma unroll
        for (int i = 0; i < 13; ++i) {
            if (i >= gn) break;
            u16 h, l; splitf(acc[i], h, l);
            hs_hi[(g0 + i) * SB + d] = h; hs_lo[(g0 + i) * SB + d] = l;
        }
    }
    // prefetch Q and K k=0 B-frags across the barrier
    bf16x8 bhQ[2], blQ[2], bhK[2], blK[2];
    loadB_q(0, bhQ, blQ);
    loadB_k(0, bhK, blK);
    __syncthreads();

    // ---- P2qk: Q+K GEMMs interleaved, shared A-frags.
    //      One loadA feeds 48 MFMAs; K's B-loads land under Q's MFMA cluster.
    //      Q -> plane0 swizzled (adj dead), K -> plane1 swizzled. ----
    {
        f32x4 accQ[2][2], accK[2][2];
        #pragma unroll
        for (int mt = 0; mt < 2; ++mt)
            #pragma unroll
            for (int nt = 0; nt < 2; ++nt) { accQ[mt][nt] = (f32x4)0.f; accK[mt][nt] = (f32x4)0.f; }

        bf16x8 ah[2], al[2];
        #pragma unroll
        for (int ki = 0; ki < 8; ++ki) {
            if (ki) {
                loadB_q(32 * ki, bhQ, blQ);
                loadB_k(32 * ki, bhK, blK);
            }
            loadA(32 * ki, ah, al);
            __builtin_amdgcn_s_setprio(1);
            #pragma unroll
            for (int j = 0; j < 2; ++j)
                #pragma unroll
                for (int mt = 0; mt < 2; ++mt)
                    accQ[mt][j] = __builtin_amdgcn_mfma_f32_16x16x32_bf16(ah[mt], bhQ[j], accQ[mt][j], 0, 0, 0);
            #pragma unroll
            for (int j = 0; j < 2; ++j)
                #pragma unroll
                for (int mt = 0; mt < 2; ++mt)
                    accQ[mt][j] = __builtin_amdgcn_mfma_f32_16x16x32_bf16(al[mt], bhQ[j], accQ[mt][j], 0, 0, 0);
            #pragma unroll
            for (int j = 0; j < 2; ++j)
                #pragma unroll
                for (int mt = 0; mt < 2; ++mt)
                    accQ[mt][j] = __builtin_amdgcn_mfma_f32_16x16x32_bf16(ah[mt], blQ[j], accQ[mt][j], 0, 0, 0);
            #pragma unroll
            for (int j = 0; j < 2; ++j)
                #pragma unroll
                for (int mt = 0; mt < 2; ++mt)
                    accK[mt][j] = __builtin_amdgcn_mfma_f32_16x16x32_bf16(ah[mt], bhK[j], accK[mt][j], 0, 0, 0);
            #pragma unroll
            for (int j = 0; j < 2; ++j)
                #pragma unroll
                for (int mt = 0; mt < 2; ++mt)
                    accK[mt][j] = __builtin_amdgcn_mfma_f32_16x16x32_bf16(al[mt], bhK[j], accK[mt][j], 0, 0, 0);
            #pragma unroll
            for (int j = 0; j < 2; ++j)
                #pragma unroll
                for (int mt = 0; mt < 2; ++mt)
                    accK[mt][j] = __builtin_amdgcn_mfma_f32_16x16x32_bf16(ah[mt], blK[j], accK[mt][j], 0, 0, 0);
            __builtin_amdgcn_s_setprio(0);
        }
        store_c(accQ, bq[wid * 32 + lm], bq[wid * 32 + 16 + lm], plane0, true, false);
        store_c(accK, bk[wid * 32 + lm], bk[wid * 32 + 16 + lm], plane1, true, false);
    }
    __syncthreads();

    // ---- P3: scores[g][h1][h2] = Q_g K_g^T / sqrt(32), kept in registers ----
    float sreg[4];
    {
        #pragma unroll
        for (int kk = 0; kk < 4; ++kk) {
            const int i = tid + kk * NTH;
            const int ii = (i < NG * 64) ? i : 0;        // lanes past 1600 compute a dummy
            const int g = ii >> 6, hh = ii & 63;
            const int jq = hh >> 3, jk = hh & 7;
            const float4* q4 = (const float4*)(plane0 + g * SQ + jq * 32);
            const float4* k4 = (const float4*)(plane1 + g * SQ + jk * 32);
            float s = 0.f;
            #pragma unroll
            for (int c = 0; c < 8; ++c) {
                float4 qa = q4[c ^ jq], ka = k4[c ^ jk];  // unswizzle on read
                s += qa.x * ka.x + qa.y * ka.y + qa.z * ka.z + qa.w * ka.w;
            }
            sreg[kk] = s * 0.17677669529663687f;
        }
    }
    __syncthreads();   // Q,K dead; plane1 reusable for ss

    // ---- P4: softmax over g (dim=1); thread owns g = part+8k at fixed col ----
    {
        const int col = tid & 63, part = tid >> 6;
        float m = -1e30f;
        #pragma unroll
        for (int kk = 0; kk < 4; ++kk)
            if (tid + kk * NTH < NG * 64) m = fmaxf(m, sreg[kk]);
        s_sm[part * 64 + col] = m;
        __syncthreads();
        float cm = -1e30f;
        #pragma unroll
        for (int p = 0; p < 8; ++p) cm = fmaxf(cm, s_sm[p * 64 + col]);
        __syncthreads();                          // all reads done before overwrite
        float den = 0.f;
        #pragma unroll
        for (int kk = 0; kk < 4; ++kk)
            if (tid + kk * NTH < NG * 64) {
                float e = expf(sreg[kk] - cm);
                sreg[kk] = e;
                den += e;
            }
        s_sm[part * 64 + col] = den;
        __syncthreads();
        float tden = 0.f;
        #pragma unroll
        for (int p = 0; p < 8; ++p) tden += s_sm[p * 64 + col];
        const float inv = 1.f / tden;
        #pragma unroll
        for (int kk = 0; kk < 4; ++kk) {
            const int i = tid + kk * NTH;
            if (i < NG * 64) plane1[i] = sreg[kk] * inv;   // ss -> K region
        }
    }
    loadB_v(0, bhB, blB);            // prefetch V k=0 B-frags across the barrier
    __syncthreads();

    // ---- P2v: V GEMM. C[25,256] -> plane0 (Q dead), unswizzled ----
    {
        f32x4 acc[2][2];
        #pragma unroll
        for (int mt = 0; mt < 2; ++mt)
            #pragma unroll
            for (int nt = 0; nt < 2; ++nt) acc[mt][nt] = (f32x4)0.f;
        run_gemm(loadA, loadB_v, bhB, blB, acc);
        store_c(acc, bv[wid * 32 + lm], bv[wid * 32 + 16 + lm], plane0, false, false);
    }
    __syncthreads();

    // ---- P5: att = w @ V (f32), write split-bf16 into hs ----
    {
        const int h1 = (tid >> 5) & 7, hd = tid & 31;   // col = d
        #pragma unroll
        for (int i = 0; i < 13; ++i) {
            if (i >= gn) break;
            const int g = g0 + i;
            float a = 0.f;
            #pragma unroll
            for (int h2 = 0; h2 < NH; ++h2)
                a += plane1[g * 64 + h1 * 8 + h2] * plane0[g * SQ + h2 * NHD + hd];
            u16 h, l; splitf(a, h, l);
            hs_hi[g * SB + d] = h; hs_lo[g * SB + d] = l;
        }
    }
    loadB_wo(0, bhB, blB);           // prefetch Wo k=0 B-frags across the barrier
    __syncthreads();

    // ---- P6: Wo GEMM. C[25,256] -> plane1 (ss dead) ----
    {
        f32x4 acc[2][2];
        #pragma unroll
        for (int mt = 0; mt < 2; ++mt)
            #pragma unroll
            for (int nt = 0; nt < 2; ++nt) acc[mt][nt] = (f32x4)0.f;
        run_gemm(loadA, loadB_wo, bhB, blB, acc);
        store_c(acc, bo[wid * 32 + lm], bo[wid * 32 + 16 + lm], plane1, false, false);
    }
    __syncthreads();

    // ---- P7: norm1; x residual re-read from global (L2/L3-hot);
    //      x1 -> hs split-bf16 (P8 A-operand) AND plane0 f32 (exact, for P9) ----
    {
        float zv[13];
        #pragma unroll
        for (int i = 0; i < 13; ++i) {
            if (i >= gn) break;
            zv[i] = plane1[(g0 + i) * SQ + d] + x[base + (g0 + i) * ND + d];
        }
        norm_stats8(zv, gn, lane, wid, tid, s_wred, s_mu, s_rsd);
        #pragma unroll
        for (int i = 0; i < 13; ++i) {
            if (i >= gn) break;
            const float x1 = af * (zv[i] - s_mu[g0 + i]) * s_rsd[g0 + i] + bef;
            u16 h, l; splitf(x1, h, l);
            hs_hi[(g0 + i) * SB + d] = h; hs_lo[(g0 + i) * SB + d] = l;
            plane0[(g0 + i) * SQ + d] = x1;          // V dead; exact copy for P9
        }
    }
    loadB_wfc(0, bhB, blB);          // prefetch Wfc k=0 B-frags across the barrier
    __syncthreads();

    // ---- P8: Wfc GEMM; epilogue relu(acc+bfc) -> plane1 ----
    {
        f32x4 acc[2][2];
        #pragma unroll
        for (int mt = 0; mt < 2; ++mt)
            #pragma unroll
            for (int nt = 0; nt < 2; ++nt) acc[mt][nt] = (f32x4)0.f;
        run_gemm(loadA, loadB_wfc, bhB, blB, acc);
        store_c(acc, bfc[wid * 32 + lm], bfc[wid * 32 + 16 + lm], plane1, false, true);
    }
    __syncthreads();

    // ---- P9: norm2 -> out; x1 exact from plane0 ----
    {
        float z2[13];
        #pragma unroll
        for (int i = 0; i < 13; ++i) {
            if (i >= gn) break;
            const int g = g0 + i;
            z2[i] = plane0[g * SQ + d] + plane1[g * SQ + d];
        }
        norm_stats8(z2, gn, lane, wid, tid, s_wred, s_mu, s_rsd);
        #pragma unroll
        for (int i = 0; i < 13; ++i) {
            if (i >= gn) break;
            out[base + (g0 + i) * ND + d] = af * (z2[i] - s_mu[g0 + i]) * s_rsd[g0 + i] + bef;
        }
    }
}

extern "C" void kernel_launch(void* const* d_in, const int* in_sizes, int n_in,
                              void* d_out, int out_size, void* d_ws, size_t ws_size,
                              hipStream_t stream) {
    (void)in_sizes; (void)n_in; (void)out_size;
    const float* x     = (const float*)d_in[0];
    const float* adj   = (const float*)d_in[1];
    const float* Wq    = (const float*)d_in[2];
    const float* bq    = (const float*)d_in[3];
    const float* Wk    = (const float*)d_in[4];
    const float* bk    = (const float*)d_in[5];
    const float* Wv    = (const float*)d_in[6];
    const float* bv    = (const float*)d_in[7];
    const float* Wo    = (const float*)d_in[8];
    const float* bo    = (const float*)d_in[9];
    const float* Wfc   = (const float*)d_in[10];
    const float* bfc   = (const float*)d_in[11];
    const float* alpha = (const float*)d_in[12];
    const float* beta  = (const float*)d_in[13];
    float* out = (float*)d_out;
    u16* ws = (u16*)d_ws;

    const bool prep = (ws_size >= WS_NEED_BYTES);

    hipFuncSetAttribute((const void*)enc_mfma<true>,
                        hipFuncAttributeMaxDynamicSharedMemorySize, SMEM_TOT);
    hipFuncSetAttribute((const void*)enc_mfma<false>,
                        hipFuncAttributeMaxDynamicSharedMemorySize, SMEM_TOT);

    if (prep) {
        prep_w<<<dim3(1280), dim3(256), 0, stream>>>(Wq, Wk, Wv, Wo, Wfc, ws);
        enc_mfma<true><<<dim3(NB * NT), dim3(NTH), SMEM_TOT, stream>>>(
            x, adj, Wq, bq, Wk, bk, Wv, bv, Wo, bo, Wfc, bfc, alpha, beta, out, ws);
    } else {
        enc_mfma<false><<<dim3(NB * NT), dim3(NTH), SMEM_TOT, stream>>>(
            x, adj, Wq, bq, Wk, bk, Wv, bv, Wo, bo, Wfc, bfc, alpha, beta, out, ws);
    }
}